// Round 10
// baseline (388.660 us; speedup 1.0000x reference)
//
#include <hip/hip_runtime.h>
#include <hip/hip_bf16.h>

// GraphSAGE 3-layer. Round 10: gather fused INTO the MFMA GEMMs.
//  memset(cnt), histrank, scanpack, fillscatter, sage0(gather+gemm0),
//  sage1(gather+gemm1), final(gather2+gemm2+log_softmax) = 7 dispatches.
// CSR: rank-based (hist stores rank; fill is atomic-free scatter);
// scan computes tile prefix directly from cnt (no tilesum kernel).

typedef short bf16x8 __attribute__((ext_vector_type(8)));
typedef float f32x4 __attribute__((ext_vector_type(4)));

static __device__ __forceinline__ unsigned short f2bf(float f) {
  unsigned u = __float_as_uint(f);
  unsigned r = u + 0x7FFFu + ((u >> 16) & 1u);  // RNE
  return (unsigned short)(r >> 16);
}
static __device__ __forceinline__ float bf2f_lo(unsigned u) {
  return __uint_as_float(u << 16);
}
static __device__ __forceinline__ float bf2f_hi(unsigned u) {
  return __uint_as_float(u & 0xFFFF0000u);
}
static __device__ __forceinline__ unsigned packbf(float lo, float hi) {
  return ((unsigned)f2bf(hi) << 16) | (unsigned)f2bf(lo);
}

// ---- sizes ----
#define E0C 900000
#define E1C 60000
#define E2C 5120
#define ETC 965120
#define HB  3770       // ceil(ETC/256)

// ---- int-workspace offsets ----
#define ROW0_OFF 0
#define ROW1_OFF 60001
#define ROW2_OFF 66002
#define CNT_OFF  67027
#define RANK_OFF 134051
#define SS0_OFF  1099171
#define SS1_OFF  1999171
#define SS2_OFF  2059171

struct TileGeom { int tin, goff, n, T; };
static __device__ __forceinline__ TileGeom tile_geom(int b) {
  TileGeom g;
  if (b < 118)      { g.tin = b;       g.goff = 0;     g.n = 60000; g.T = 118; }
  else if (b < 130) { g.tin = b - 118; g.goff = 60000; g.n = 6000;  g.T = 12; }
  else              { g.tin = b - 130; g.goff = 66000; g.n = 1024;  g.T = 2; }
  return g;
}

// ---------- hist with rank capture ----------
__global__ __launch_bounds__(256) void histrank_k(
    const int* __restrict__ d0, const int* __restrict__ d1, const int* __restrict__ d2,
    int* __restrict__ cnt, int* __restrict__ rank) {
  int t = blockIdx.x * 256 + threadIdx.x;
  if (t < E0C) {
    rank[t] = atomicAdd(&cnt[d0[t]], 1);
  } else if (t < E0C + E1C) {
    rank[t] = atomicAdd(&cnt[60000 + d1[t - E0C]], 1);
  } else if (t < ETC) {
    rank[t] = atomicAdd(&cnt[66000 + d2[t - E0C - E1C]], 1);
  }
}

// ---------- per-tile scan (prefix direct from cnt) + weight packing ----------
__global__ __launch_bounds__(256) void scanpack_k(
    const int* __restrict__ cnt,
    int* __restrict__ row0, int* __restrict__ row1, int* __restrict__ row2,
    const float* __restrict__ Wl0, const float* __restrict__ Wr0,
    unsigned short* __restrict__ bm0,
    const float* __restrict__ Wl1, const float* __restrict__ Wr1,
    unsigned short* __restrict__ bm1) {
  const int b = blockIdx.x;
  const int tid = threadIdx.x;
  if (b < 132) {
    __shared__ int sc[256];
    const TileGeom g = tile_geom(b);
    int* row = (b < 118) ? row0 : (b < 130 ? row1 : row2);
    // prefix over earlier elements of this layer
    int p = 0;
    const int lim = g.tin * 512;
    for (int i = tid; i < lim; i += 256) p += cnt[g.goff + i];
    sc[tid] = p;
    __syncthreads();
    for (int off = 128; off; off >>= 1) {
      if (tid < off) sc[tid] += sc[tid + off];
      __syncthreads();
    }
    const int pref = sc[0];
    __syncthreads();
    // 512-element pair scan
    const int i0 = g.tin * 512 + 2 * tid;
    const int e0 = (i0 < g.n) ? cnt[g.goff + i0] : 0;
    const int e1 = (i0 + 1 < g.n) ? cnt[g.goff + i0 + 1] : 0;
    sc[tid] = e0 + e1;
    __syncthreads();
    for (int off = 1; off < 256; off <<= 1) {
      int v = (tid >= off) ? sc[tid - off] : 0;
      __syncthreads();
      sc[tid] += v;
      __syncthreads();
    }
    const int excl = sc[tid] - (e0 + e1);
    const int o0 = pref + excl;
    const int o1 = o0 + e0;
    if (i0 < g.n) row[i0] = o0;
    if (i0 + 1 < g.n) row[i0 + 1] = o1;
    if (g.tin == g.T - 1 && tid == 255) row[g.n] = pref + sc[255];
  } else {
    int j = b - 132;
    int n = tid;
    if (j < 224) {
      int k = j;
      float v = 0.f;
      if (k < 100) v = Wl0[(size_t)k * 256 + n];
      else if (k >= 112 && k < 212) v = Wr0[(size_t)(k - 112) * 256 + n];
      bm0[(((size_t)(k >> 3) * 256) + n) * 8 + (k & 7)] = f2bf(v);
    } else {
      int k = j - 224;
      float v = (k < 256) ? Wl1[(size_t)k * 256 + n] : Wr1[(size_t)(k - 256) * 256 + n];
      bm1[(((size_t)(k >> 3) * 256) + n) * 8 + (k & 7)] = f2bf(v);
    }
  }
}

// ---------- atomic-free fill (rank-based) ----------
__global__ __launch_bounds__(256) void fillscatter_k(
    const int* __restrict__ d0, const int* __restrict__ d1, const int* __restrict__ d2,
    const int* __restrict__ s0, const int* __restrict__ s1, const int* __restrict__ s2,
    const int* __restrict__ row0, const int* __restrict__ row1,
    const int* __restrict__ row2, const int* __restrict__ rank,
    int* __restrict__ o0, int* __restrict__ o1, int* __restrict__ o2) {
  int t = blockIdx.x * 256 + threadIdx.x;
  if (t < E0C) {
    o0[row0[d0[t]] + rank[t]] = s0[t];
  } else if (t < E0C + E1C) {
    int e = t - E0C;
    o1[row1[d1[e]] + rank[t]] = s1[e];
  } else if (t < ETC) {
    int e = t - E0C - E1C;
    o2[row2[d2[e]] + rank[t]] = s2[e];
  }
}

// ---------- sage0: fused gather-mean + GEMM layer 0 ----------
// A-tile [64][224] = [mean(100) pad | x(100) pad] built in LDS by this block,
// then C = relu(A @ bm0 + b0) -> h0b (bf16). M = 60000.
__global__ __launch_bounds__(256) void sage0_k(
    const float* __restrict__ x, const int* __restrict__ ss,
    const int* __restrict__ rs, const unsigned short* __restrict__ Bp,
    const float* __restrict__ bias, unsigned short* __restrict__ h0b, int M) {
  constexpr int LDA = 232;   // 224 + 8
  __shared__ unsigned short As[64 * LDA];
  const int row0 = blockIdx.x * 64;
  const int wid = threadIdx.x >> 6;
  const int f = threadIdx.x & 63;
  const int k1 = f + 64;

  // staging: wave wid builds rows wid*16 .. wid*16+15
  for (int i = 0; i < 16; ++i) {
    const int r = wid * 16 + i;
    const int gr = row0 + r;
    float a0 = 0.f, a1 = 0.f;
    float xv0 = 0.f, xv1 = 0.f;
    if (gr < M) {
      const int lo = rs[gr];
      const int hi = rs[gr + 1];
      int e = lo;
      for (; e + 4 <= hi; e += 4) {
        const float* p0 = x + (size_t)ss[e] * 100;
        const float* p1 = x + (size_t)ss[e + 1] * 100;
        const float* p2 = x + (size_t)ss[e + 2] * 100;
        const float* p3 = x + (size_t)ss[e + 3] * 100;
        a0 += (p0[f] + p1[f]) + (p2[f] + p3[f]);
        if (k1 < 100) a1 += (p0[k1] + p1[k1]) + (p2[k1] + p3[k1]);
      }
      for (; e < hi; ++e) {
        const float* p0 = x + (size_t)ss[e] * 100;
        a0 += p0[f];
        if (k1 < 100) a1 += p0[k1];
      }
      const float inv = 1.f / (float)max(hi - lo, 1);
      a0 *= inv; a1 *= inv;
      xv0 = x[(size_t)gr * 100 + f];
      if (k1 < 100) xv1 = x[(size_t)gr * 100 + k1];
    }
    unsigned short* arow = &As[r * LDA];
    arow[f] = f2bf(a0);
    if (k1 < 112) arow[k1] = (k1 < 100) ? f2bf(a1) : (unsigned short)0;
    arow[112 + f] = f2bf(xv0);
    if (k1 < 112) arow[112 + k1] = (k1 < 100) ? f2bf(xv1) : (unsigned short)0;
  }
  __syncthreads();

  // MFMA: 4 row-tiles x 4 col-tiles per wave, K = 224 (7 chunks of 32)
  const int l15 = f & 15;
  const int lhi = f >> 4;
  f32x4 acc[4][4];
#pragma unroll
  for (int rt = 0; rt < 4; ++rt)
#pragma unroll
    for (int ct = 0; ct < 4; ++ct) acc[rt][ct] = (f32x4){0.f, 0.f, 0.f, 0.f};

  for (int kc = 0; kc < 7; ++kc) {
    bf16x8 a[4], b[4];
#pragma unroll
    for (int rt = 0; rt < 4; ++rt)
      a[rt] = *reinterpret_cast<const bf16x8*>(
          &As[(rt * 16 + l15) * LDA + kc * 32 + lhi * 8]);
#pragma unroll
    for (int ct = 0; ct < 4; ++ct) {
      int n = wid * 64 + ct * 16 + l15;
      b[ct] = *reinterpret_cast<const bf16x8*>(
          Bp + ((size_t)(kc * 4 + lhi) * 256 + n) * 8);
    }
#pragma unroll
    for (int rt = 0; rt < 4; ++rt)
#pragma unroll
      for (int ct = 0; ct < 4; ++ct)
        acc[rt][ct] = __builtin_amdgcn_mfma_f32_16x16x32_bf16(a[rt], b[ct],
                                                              acc[rt][ct], 0, 0, 0);
  }

#pragma unroll
  for (int rt = 0; rt < 4; ++rt) {
#pragma unroll
    for (int ct = 0; ct < 4; ++ct) {
      int col = wid * 64 + ct * 16 + l15;
      float bv = bias[col];
#pragma unroll
      for (int r = 0; r < 4; ++r) {
        int row = row0 + rt * 16 + lhi * 4 + r;
        if (row < M)
          h0b[(size_t)row * 256 + col] = f2bf(fmaxf(acc[rt][ct][r] + bv, 0.f));
      }
    }
  }
}

// ---------- sage1: fused gather-mean + GEMM layer 1 ----------
// A-tile [32][512] = [mean(256) | x(256)] from bf16 h0b; C = relu(A@bm1+b1) -> h1 f32.
__global__ __launch_bounds__(256) void sage1_k(
    const unsigned* __restrict__ h0bu, const int* __restrict__ ss,
    const int* __restrict__ rs, const unsigned short* __restrict__ Bp,
    const float* __restrict__ bias, float* __restrict__ h1, int M) {
  constexpr int LDA = 520;   // shorts (512 + 8)
  __shared__ unsigned short As[32 * LDA];
  unsigned* Asu = (unsigned*)As;
  const int row0 = blockIdx.x * 32;
  const int wid = threadIdx.x >> 6;
  const int f = threadIdx.x & 63;

  // staging: wave wid builds rows wid*8 .. wid*8+7
  for (int i = 0; i < 8; ++i) {
    const int r = wid * 8 + i;
    const int gr = row0 + r;
    float l0 = 0.f, hh0 = 0.f, l1 = 0.f, hh1 = 0.f;
    unsigned xv0 = 0, xv1 = 0;
    float inv = 0.f;
    if (gr < M) {
      const int lo = rs[gr];
      const int hi = rs[gr + 1];
      int e = lo;
      for (; e + 2 <= hi; e += 2) {
        const unsigned* p0 = h0bu + (size_t)ss[e] * 128;
        const unsigned* p1 = h0bu + (size_t)ss[e + 1] * 128;
        unsigned u0 = p0[f], v0 = p0[f + 64];
        unsigned u1 = p1[f], v1 = p1[f + 64];
        l0 += bf2f_lo(u0) + bf2f_lo(u1);
        hh0 += bf2f_hi(u0) + bf2f_hi(u1);
        l1 += bf2f_lo(v0) + bf2f_lo(v1);
        hh1 += bf2f_hi(v0) + bf2f_hi(v1);
      }
      for (; e < hi; ++e) {
        const unsigned* p0 = h0bu + (size_t)ss[e] * 128;
        unsigned u0 = p0[f], v0 = p0[f + 64];
        l0 += bf2f_lo(u0); hh0 += bf2f_hi(u0);
        l1 += bf2f_lo(v0); hh1 += bf2f_hi(v0);
      }
      inv = 1.f / (float)max(hi - lo, 1);
      xv0 = h0bu[(size_t)gr * 128 + f];
      xv1 = h0bu[(size_t)gr * 128 + 64 + f];
    }
    unsigned* arow = Asu + r * 260;  // 520 shorts = 260 uints
    arow[f] = packbf(l0 * inv, hh0 * inv);
    arow[64 + f] = packbf(l1 * inv, hh1 * inv);
    arow[128 + f] = xv0;
    arow[192 + f] = xv1;
  }
  __syncthreads();

  // MFMA: 2 row-tiles x 4 col-tiles per wave, K = 512 (16 chunks of 32)
  const int l15 = f & 15;
  const int lhi = f >> 4;
  f32x4 acc[2][4];
#pragma unroll
  for (int rt = 0; rt < 2; ++rt)
#pragma unroll
    for (int ct = 0; ct < 4; ++ct) acc[rt][ct] = (f32x4){0.f, 0.f, 0.f, 0.f};

  for (int kc = 0; kc < 16; ++kc) {
    bf16x8 a[2], b[4];
#pragma unroll
    for (int rt = 0; rt < 2; ++rt)
      a[rt] = *reinterpret_cast<const bf16x8*>(
          &As[(rt * 16 + l15) * LDA + kc * 32 + lhi * 8]);
#pragma unroll
    for (int ct = 0; ct < 4; ++ct) {
      int n = wid * 64 + ct * 16 + l15;
      b[ct] = *reinterpret_cast<const bf16x8*>(
          Bp + ((size_t)(kc * 4 + lhi) * 256 + n) * 8);
    }
#pragma unroll
    for (int rt = 0; rt < 2; ++rt)
#pragma unroll
      for (int ct = 0; ct < 4; ++ct)
        acc[rt][ct] = __builtin_amdgcn_mfma_f32_16x16x32_bf16(a[rt], b[ct],
                                                              acc[rt][ct], 0, 0, 0);
  }

#pragma unroll
  for (int rt = 0; rt < 2; ++rt) {
#pragma unroll
    for (int ct = 0; ct < 4; ++ct) {
      int col = wid * 64 + ct * 16 + l15;
      float bv = bias[col];
#pragma unroll
      for (int r = 0; r < 4; ++r) {
        int row = row0 + rt * 16 + lhi * 4 + r;
        if (row < M)
          h1[(size_t)row * 256 + col] = fmaxf(acc[rt][ct][r] + bv, 0.f);
      }
    }
  }
}

// ---------- final: fused gather2 + dual GEMM (512 -> 47) + log_softmax ----------
__global__ __launch_bounds__(64) void final_fused_k(
    const float* __restrict__ h1, const int* __restrict__ ss,
    const int* __restrict__ rs, const float* __restrict__ Wl,
    const float* __restrict__ Wr, const float* __restrict__ bb,
    float* __restrict__ out) {
  __shared__ float sm[4][256];
  __shared__ float sx[4][256];
  const int i0 = blockIdx.x * 4;
  const int f = threadIdx.x;
#pragma unroll
  for (int r = 0; r < 4; ++r) {
    const int i = i0 + r;
    const int lo = rs[i];
    const int hi = rs[i + 1];
    float a0 = 0.f, a1 = 0.f, a2 = 0.f, a3 = 0.f;
    for (int e = lo; e < hi; ++e) {
      const float* p = h1 + (size_t)ss[e] * 256;
      a0 += p[f]; a1 += p[f + 64]; a2 += p[f + 128]; a3 += p[f + 192];
    }
    const float inv = 1.f / (float)max(hi - lo, 1);
    sm[r][f] = a0 * inv; sm[r][f + 64] = a1 * inv;
    sm[r][f + 128] = a2 * inv; sm[r][f + 192] = a3 * inv;
    const float* q = h1 + (size_t)i * 256;
    sx[r][f] = q[f]; sx[r][f + 64] = q[f + 64];
    sx[r][f + 128] = q[f + 128]; sx[r][f + 192] = q[f + 192];
  }
  __syncthreads();

  const int j = f;
  float acc[4] = {-1e30f, -1e30f, -1e30f, -1e30f};
  if (j < 47) {
    float b = bb[j];
    acc[0] = b; acc[1] = b; acc[2] = b; acc[3] = b;
    for (int k = 0; k < 256; ++k) {
      float wl = Wl[k * 47 + j];
      float wr = Wr[k * 47 + j];
#pragma unroll
      for (int r = 0; r < 4; ++r) acc[r] += sm[r][k] * wl + sx[r][k] * wr;
    }
  }
#pragma unroll
  for (int r = 0; r < 4; ++r) {
    float m = acc[r];
#pragma unroll
    for (int off = 32; off; off >>= 1) m = fmaxf(m, __shfl_xor(m, off));
    float e = (j < 47) ? expf(acc[r] - m) : 0.f;
    float s = e;
#pragma unroll
    for (int off = 32; off; off >>= 1) s += __shfl_xor(s, off);
    if (j < 47) out[(size_t)(i0 + r) * 47 + j] = acc[r] - m - logf(s);
  }
}

extern "C" void kernel_launch(void* const* d_in, const int* in_sizes, int n_in,
                              void* d_out, int out_size, void* d_ws, size_t ws_size,
                              hipStream_t stream) {
  const float* x    = (const float*)d_in[0];
  const int*   src0 = (const int*)d_in[1];
  const int*   dst0 = (const int*)d_in[2];
  const int*   src1 = (const int*)d_in[3];
  const int*   dst1 = (const int*)d_in[4];
  const int*   src2 = (const int*)d_in[5];
  const int*   dst2 = (const int*)d_in[6];
  const float* Wl0  = (const float*)d_in[7];
  const float* Wr0  = (const float*)d_in[8];
  const float* b0   = (const float*)d_in[9];
  const float* Wl1  = (const float*)d_in[10];
  const float* Wr1  = (const float*)d_in[11];
  const float* b1   = (const float*)d_in[12];
  const float* Wl2  = (const float*)d_in[13];
  const float* Wr2  = (const float*)d_in[14];
  const float* b2   = (const float*)d_in[15];
  float* out = (float*)d_out;

  const int N0 = 60000, N1 = 6000, N2 = 1024;

  // ---- workspace carve-up (bytes, 256-aligned) ----
  char* base = (char*)d_ws;
  unsigned short* bm0 = (unsigned short*)(base);             // 28x256x8 bf16
  unsigned short* bm1 = (unsigned short*)(base + 114688);    // 64x256x8 bf16
  unsigned short* h0b = (unsigned short*)(base + 376832);    // 60032 x 256 bf16
  unsigned*       h0bu= (unsigned*)(base + 376832);
  float* h1           = (float*)(base + 31113216);           // 6016 x 256 f32
  int* iw             = (int*)(base + 37273600);
  int* row0 = iw + ROW0_OFF;
  int* row1 = iw + ROW1_OFF;
  int* row2 = iw + ROW2_OFF;
  int* cnt  = iw + CNT_OFF;
  int* rank = iw + RANK_OFF;
  int* ss0  = iw + SS0_OFF;
  int* ss1  = iw + SS1_OFF;
  int* ss2  = iw + SS2_OFF;

  // ---- CSR build ----
  hipMemsetAsync(cnt, 0, (size_t)67024 * sizeof(int), stream);
  histrank_k<<<HB, 256, 0, stream>>>(dst0, dst1, dst2, cnt, rank);
  scanpack_k<<<132 + 736, 256, 0, stream>>>(cnt, row0, row1, row2,
                                            Wl0, Wr0, bm0, Wl1, Wr1, bm1);
  fillscatter_k<<<HB, 256, 0, stream>>>(dst0, dst1, dst2, src0, src1, src2,
                                        row0, row1, row2, rank, ss0, ss1, ss2);

  // ---- Layer 0 (fused gather+GEMM) ----
  sage0_k<<<(N0 + 63) / 64, 256, 0, stream>>>(x, ss0, row0, bm0, b0, h0b, N0);

  // ---- Layer 1 (fused gather+GEMM) ----
  sage1_k<<<(N1 + 31) / 32, 256, 0, stream>>>(h0bu, ss1, row1, bm1, b1, h1, N1);

  // ---- Layer 2 (fused final) ----
  final_fused_k<<<N2 / 4, 64, 0, stream>>>(h1, ss2, row2, Wl2, Wr2, b2, out);
}

// Round 11
// 277.099 us; speedup vs baseline: 1.4026x; 1.4026x over previous
//
#include <hip/hip_runtime.h>
#include <hip/hip_bf16.h>

// GraphSAGE 3-layer. Round 11: best-measured pieces, split kernels.
//  memset(cnt), histrank, scanpack, fillscatter,            (CSR, ~50 us)
//  gather0 (88.6 us, wave-per-row), gemm0 (bf16 out, ~33),
//  gather1 (bf16, ~15), gemm1 (~8), final (~11)  = 9 dispatches.

typedef short bf16x8 __attribute__((ext_vector_type(8)));
typedef float f32x4 __attribute__((ext_vector_type(4)));

static __device__ __forceinline__ unsigned short f2bf(float f) {
  unsigned u = __float_as_uint(f);
  unsigned r = u + 0x7FFFu + ((u >> 16) & 1u);  // RNE
  return (unsigned short)(r >> 16);
}
static __device__ __forceinline__ float bf2f_lo(unsigned u) {
  return __uint_as_float(u << 16);
}
static __device__ __forceinline__ float bf2f_hi(unsigned u) {
  return __uint_as_float(u & 0xFFFF0000u);
}
static __device__ __forceinline__ unsigned packbf(float lo, float hi) {
  return ((unsigned)f2bf(hi) << 16) | (unsigned)f2bf(lo);
}

// ---- sizes ----
#define E0C 900000
#define E1C 60000
#define E2C 5120
#define ETC 965120
#define HB  3770       // ceil(ETC/256)

// ---- int-workspace offsets ----
#define ROW0_OFF 0
#define ROW1_OFF 60001
#define ROW2_OFF 66002
#define CNT_OFF  67027
#define RANK_OFF 134051
#define SS0_OFF  1099171
#define SS1_OFF  1999171
#define SS2_OFF  2059171

struct TileGeom { int tin, goff, n, T; };
static __device__ __forceinline__ TileGeom tile_geom(int b) {
  TileGeom g;
  if (b < 118)      { g.tin = b;       g.goff = 0;     g.n = 60000; g.T = 118; }
  else if (b < 130) { g.tin = b - 118; g.goff = 60000; g.n = 6000;  g.T = 12; }
  else              { g.tin = b - 130; g.goff = 66000; g.n = 1024;  g.T = 2; }
  return g;
}

// ---------- hist with rank capture ----------
__global__ __launch_bounds__(256) void histrank_k(
    const int* __restrict__ d0, const int* __restrict__ d1, const int* __restrict__ d2,
    int* __restrict__ cnt, int* __restrict__ rank) {
  int t = blockIdx.x * 256 + threadIdx.x;
  if (t < E0C) {
    rank[t] = atomicAdd(&cnt[d0[t]], 1);
  } else if (t < E0C + E1C) {
    rank[t] = atomicAdd(&cnt[60000 + d1[t - E0C]], 1);
  } else if (t < ETC) {
    rank[t] = atomicAdd(&cnt[66000 + d2[t - E0C - E1C]], 1);
  }
}

// ---------- per-tile scan (prefix direct from cnt) + weight packing ----------
__global__ __launch_bounds__(256) void scanpack_k(
    const int* __restrict__ cnt,
    int* __restrict__ row0, int* __restrict__ row1, int* __restrict__ row2,
    const float* __restrict__ Wl0, const float* __restrict__ Wr0,
    unsigned short* __restrict__ bm0,
    const float* __restrict__ Wl1, const float* __restrict__ Wr1,
    unsigned short* __restrict__ bm1) {
  const int b = blockIdx.x;
  const int tid = threadIdx.x;
  if (b < 132) {
    __shared__ int sc[256];
    const TileGeom g = tile_geom(b);
    int* row = (b < 118) ? row0 : (b < 130 ? row1 : row2);
    int p = 0;
    const int lim = g.tin * 512;
    for (int i = tid; i < lim; i += 256) p += cnt[g.goff + i];
    sc[tid] = p;
    __syncthreads();
    for (int off = 128; off; off >>= 1) {
      if (tid < off) sc[tid] += sc[tid + off];
      __syncthreads();
    }
    const int pref = sc[0];
    __syncthreads();
    const int i0 = g.tin * 512 + 2 * tid;
    const int e0 = (i0 < g.n) ? cnt[g.goff + i0] : 0;
    const int e1 = (i0 + 1 < g.n) ? cnt[g.goff + i0 + 1] : 0;
    sc[tid] = e0 + e1;
    __syncthreads();
    for (int off = 1; off < 256; off <<= 1) {
      int v = (tid >= off) ? sc[tid - off] : 0;
      __syncthreads();
      sc[tid] += v;
      __syncthreads();
    }
    const int excl = sc[tid] - (e0 + e1);
    const int o0 = pref + excl;
    const int o1 = o0 + e0;
    if (i0 < g.n) row[i0] = o0;
    if (i0 + 1 < g.n) row[i0 + 1] = o1;
    if (g.tin == g.T - 1 && tid == 255) row[g.n] = pref + sc[255];
  } else {
    int j = b - 132;
    int n = tid;
    if (j < 224) {
      int k = j;
      float v = 0.f;
      if (k < 100) v = Wl0[(size_t)k * 256 + n];
      else if (k >= 112 && k < 212) v = Wr0[(size_t)(k - 112) * 256 + n];
      bm0[(((size_t)(k >> 3) * 256) + n) * 8 + (k & 7)] = f2bf(v);
    } else {
      int k = j - 224;
      float v = (k < 256) ? Wl1[(size_t)k * 256 + n] : Wr1[(size_t)(k - 256) * 256 + n];
      bm1[(((size_t)(k >> 3) * 256) + n) * 8 + (k & 7)] = f2bf(v);
    }
  }
}

// ---------- atomic-free fill (rank-based) ----------
__global__ __launch_bounds__(256) void fillscatter_k(
    const int* __restrict__ d0, const int* __restrict__ d1, const int* __restrict__ d2,
    const int* __restrict__ s0, const int* __restrict__ s1, const int* __restrict__ s2,
    const int* __restrict__ row0, const int* __restrict__ row1,
    const int* __restrict__ row2, const int* __restrict__ rank,
    int* __restrict__ o0, int* __restrict__ o1, int* __restrict__ o2) {
  int t = blockIdx.x * 256 + threadIdx.x;
  if (t < E0C) {
    o0[row0[d0[t]] + rank[t]] = s0[t];
  } else if (t < E0C + E1C) {
    int e = t - E0C;
    o1[row1[d1[e]] + rank[t]] = s1[e];
  } else if (t < ETC) {
    int e = t - E0C - E1C;
    o2[row2[d2[e]] + rank[t]] = s2[e];
  }
}

// ---------- gather0: wave-per-row mean + self-row conversion, f32 in ----------
// am[w][0..100) = bf16(mean), am[w][112..212) = bf16(x[w]); pitch 224.
__global__ __launch_bounds__(256) void gather_fused_k(
    const float* __restrict__ x, const int* __restrict__ ss,
    const int* __restrict__ rs, unsigned short* __restrict__ am, int n) {
  int idx = blockIdx.x * 256 + threadIdx.x;
  int w = idx >> 6;
  int f = idx & 63;
  if (w >= n) return;
  const int lo = rs[w];
  const int hi = rs[w + 1];
  float acc0 = 0.f, acc1 = 0.f;
  const int k1 = f + 64;
  int e = lo;
  for (; e + 4 <= hi; e += 4) {
    const float* p0 = x + (size_t)ss[e] * 100;
    const float* p1 = x + (size_t)ss[e + 1] * 100;
    const float* p2 = x + (size_t)ss[e + 2] * 100;
    const float* p3 = x + (size_t)ss[e + 3] * 100;
    acc0 += (p0[f] + p1[f]) + (p2[f] + p3[f]);
    if (k1 < 100) acc1 += (p0[k1] + p1[k1]) + (p2[k1] + p3[k1]);
  }
  for (; e < hi; ++e) {
    const float* p0 = x + (size_t)ss[e] * 100;
    acc0 += p0[f];
    if (k1 < 100) acc1 += p0[k1];
  }
  const float inv = 1.f / (float)max(hi - lo, 1);
  unsigned short* arow = am + (size_t)w * 224;
  arow[f] = f2bf(acc0 * inv);
  if (k1 < 112) arow[k1] = (k1 < 100) ? f2bf(acc1 * inv) : (unsigned short)0;
  const float* xrow = x + (size_t)w * 100;
  arow[112 + f] = f2bf(xrow[f]);
  if (k1 < 112) arow[112 + k1] = (k1 < 100) ? f2bf(xrow[k1]) : (unsigned short)0;
}

// ---------- gather1: wave-per-row mean over bf16 h0 rows ----------
__global__ __launch_bounds__(256) void gather_mean_b16_k(
    const unsigned* __restrict__ xbu, const int* __restrict__ ss,
    const int* __restrict__ rs, unsigned* __restrict__ meanu, int n) {
  int idx = blockIdx.x * 256 + threadIdx.x;
  int w = idx >> 6;
  int f = idx & 63;
  if (w >= n) return;
  const int lo = rs[w];
  const int hi = rs[w + 1];
  float a0l = 0.f, a0h = 0.f, a1l = 0.f, a1h = 0.f;
  int e = lo;
  for (; e + 2 <= hi; e += 2) {
    const unsigned* p0 = xbu + (size_t)ss[e] * 128;
    const unsigned* p1 = xbu + (size_t)ss[e + 1] * 128;
    unsigned u0a = p0[f], u0b = p0[f + 64];
    unsigned u1a = p1[f], u1b = p1[f + 64];
    a0l += bf2f_lo(u0a) + bf2f_lo(u1a);
    a0h += bf2f_hi(u0a) + bf2f_hi(u1a);
    a1l += bf2f_lo(u0b) + bf2f_lo(u1b);
    a1h += bf2f_hi(u0b) + bf2f_hi(u1b);
  }
  for (; e < hi; ++e) {
    const unsigned* p0 = xbu + (size_t)ss[e] * 128;
    unsigned ua = p0[f], ub = p0[f + 64];
    a0l += bf2f_lo(ua); a0h += bf2f_hi(ua);
    a1l += bf2f_lo(ub); a1h += bf2f_hi(ub);
  }
  const float inv = 1.f / (float)max(hi - lo, 1);
  meanu[(size_t)w * 128 + f] = packbf(a0l * inv, a0h * inv);
  meanu[(size_t)w * 128 + f + 64] = packbf(a1l * inv, a1h * inv);
}

// ---------- MFMA GEMM, two-pointer A, optional bf16 out ----------
template <int KPAD, int C1CH, int MBLK, bool RELU, bool OUTBF>
__global__ __launch_bounds__(256) void gemm_mfma_k(
    const unsigned short* __restrict__ A1, const unsigned short* __restrict__ A2,
    const unsigned short* __restrict__ Bp, const float* __restrict__ bias,
    void* __restrict__ outv, int M, int p1, int p2) {
  constexpr int LDA = KPAD + 8;
  constexpr int CPR = KPAD / 8;
  constexpr int RT = MBLK / 16;
  constexpr int NKC = KPAD / 32;
  __shared__ unsigned short As[MBLK * LDA];

  const int row0 = blockIdx.x * MBLK;
  for (int t = threadIdx.x; t < MBLK * CPR; t += 256) {
    int r = t / CPR;
    int c = t - r * CPR;
    const unsigned short* src = (c < C1CH)
        ? (A1 + (size_t)(row0 + r) * p1 + c * 8)
        : (A2 + (size_t)(row0 + r) * p2 + (c - C1CH) * 8);
    *reinterpret_cast<uint4*>(&As[r * LDA + c * 8]) =
        *reinterpret_cast<const uint4*>(src);
  }
  __syncthreads();

  const int wid = threadIdx.x >> 6;
  const int l = threadIdx.x & 63;
  const int l15 = l & 15;
  const int lhi = l >> 4;

  f32x4 acc[RT][4];
#pragma unroll
  for (int rt = 0; rt < RT; ++rt)
#pragma unroll
    for (int ct = 0; ct < 4; ++ct) acc[rt][ct] = (f32x4){0.f, 0.f, 0.f, 0.f};

  for (int kc = 0; kc < NKC; ++kc) {
    bf16x8 a[RT], b[4];
#pragma unroll
    for (int rt = 0; rt < RT; ++rt)
      a[rt] = *reinterpret_cast<const bf16x8*>(
          &As[(rt * 16 + l15) * LDA + kc * 32 + lhi * 8]);
#pragma unroll
    for (int ct = 0; ct < 4; ++ct) {
      int n = wid * 64 + ct * 16 + l15;
      b[ct] = *reinterpret_cast<const bf16x8*>(
          Bp + ((size_t)(kc * 4 + lhi) * 256 + n) * 8);
    }
#pragma unroll
    for (int rt = 0; rt < RT; ++rt)
#pragma unroll
      for (int ct = 0; ct < 4; ++ct)
        acc[rt][ct] = __builtin_amdgcn_mfma_f32_16x16x32_bf16(a[rt], b[ct],
                                                              acc[rt][ct], 0, 0, 0);
  }

#pragma unroll
  for (int rt = 0; rt < RT; ++rt) {
#pragma unroll
    for (int ct = 0; ct < 4; ++ct) {
      int col = wid * 64 + ct * 16 + l15;
      float bv = bias[col];
#pragma unroll
      for (int r = 0; r < 4; ++r) {
        int row = row0 + rt * 16 + lhi * 4 + r;
        if (row < M) {
          float v = acc[rt][ct][r] + bv;
          if (RELU) v = fmaxf(v, 0.f);
          if (OUTBF)
            ((unsigned short*)outv)[(size_t)row * 256 + col] = f2bf(v);
          else
            ((float*)outv)[(size_t)row * 256 + col] = v;
        }
      }
    }
  }
}

// ---------- final: fused gather2 + dual GEMM (512 -> 47) + log_softmax ----------
__global__ __launch_bounds__(64) void final_fused_k(
    const float* __restrict__ h1, const int* __restrict__ ss,
    const int* __restrict__ rs, const float* __restrict__ Wl,
    const float* __restrict__ Wr, const float* __restrict__ bb,
    float* __restrict__ out) {
  __shared__ float sm[4][256];
  __shared__ float sx[4][256];
  const int i0 = blockIdx.x * 4;
  const int f = threadIdx.x;
#pragma unroll
  for (int r = 0; r < 4; ++r) {
    const int i = i0 + r;
    const int lo = rs[i];
    const int hi = rs[i + 1];
    float a0 = 0.f, a1 = 0.f, a2 = 0.f, a3 = 0.f;
    for (int e = lo; e < hi; ++e) {
      const float* p = h1 + (size_t)ss[e] * 256;
      a0 += p[f]; a1 += p[f + 64]; a2 += p[f + 128]; a3 += p[f + 192];
    }
    const float inv = 1.f / (float)max(hi - lo, 1);
    sm[r][f] = a0 * inv; sm[r][f + 64] = a1 * inv;
    sm[r][f + 128] = a2 * inv; sm[r][f + 192] = a3 * inv;
    const float* q = h1 + (size_t)i * 256;
    sx[r][f] = q[f]; sx[r][f + 64] = q[f + 64];
    sx[r][f + 128] = q[f + 128]; sx[r][f + 192] = q[f + 192];
  }
  __syncthreads();

  const int j = f;
  float acc[4] = {-1e30f, -1e30f, -1e30f, -1e30f};
  if (j < 47) {
    float b = bb[j];
    acc[0] = b; acc[1] = b; acc[2] = b; acc[3] = b;
    for (int k = 0; k < 256; ++k) {
      float wl = Wl[k * 47 + j];
      float wr = Wr[k * 47 + j];
#pragma unroll
      for (int r = 0; r < 4; ++r) acc[r] += sm[r][k] * wl + sx[r][k] * wr;
    }
  }
#pragma unroll
  for (int r = 0; r < 4; ++r) {
    float m = acc[r];
#pragma unroll
    for (int off = 32; off; off >>= 1) m = fmaxf(m, __shfl_xor(m, off));
    float e = (j < 47) ? expf(acc[r] - m) : 0.f;
    float s = e;
#pragma unroll
    for (int off = 32; off; off >>= 1) s += __shfl_xor(s, off);
    if (j < 47) out[(size_t)(i0 + r) * 47 + j] = acc[r] - m - logf(s);
  }
}

extern "C" void kernel_launch(void* const* d_in, const int* in_sizes, int n_in,
                              void* d_out, int out_size, void* d_ws, size_t ws_size,
                              hipStream_t stream) {
  const float* x    = (const float*)d_in[0];
  const int*   src0 = (const int*)d_in[1];
  const int*   dst0 = (const int*)d_in[2];
  const int*   src1 = (const int*)d_in[3];
  const int*   dst1 = (const int*)d_in[4];
  const int*   src2 = (const int*)d_in[5];
  const int*   dst2 = (const int*)d_in[6];
  const float* Wl0  = (const float*)d_in[7];
  const float* Wr0  = (const float*)d_in[8];
  const float* b0   = (const float*)d_in[9];
  const float* Wl1  = (const float*)d_in[10];
  const float* Wr1  = (const float*)d_in[11];
  const float* b1   = (const float*)d_in[12];
  const float* Wl2  = (const float*)d_in[13];
  const float* Wr2  = (const float*)d_in[14];
  const float* b2   = (const float*)d_in[15];
  float* out = (float*)d_out;

  const int N0 = 60000, N1 = 6000, N2 = 1024;

  // ---- workspace carve-up (bytes, 256-aligned) ----
  char* base = (char*)d_ws;
  unsigned short* bm0  = (unsigned short*)(base);            // 28x256x8 bf16
  unsigned short* bm1  = (unsigned short*)(base + 114688);   // 64x256x8 bf16
  unsigned short* am0  = (unsigned short*)(base + 376832);   // 60032 x 224 bf16
  unsigned short* h0b  = (unsigned short*)(base + 27271168); // 60032 x 256 bf16
  unsigned*       h0bu = (unsigned*)(base + 27271168);
  unsigned short* mean1= (unsigned short*)(base + 58007552); // 6016 x 256 bf16
  unsigned*       mean1u=(unsigned*)(base + 58007552);
  float* h1            = (float*)(base + 61087744);          // 6016 x 256 f32
  int* iw              = (int*)(base + 67248128);
  int* row0 = iw + ROW0_OFF;
  int* row1 = iw + ROW1_OFF;
  int* row2 = iw + ROW2_OFF;
  int* cnt  = iw + CNT_OFF;
  int* rank = iw + RANK_OFF;
  int* ss0  = iw + SS0_OFF;
  int* ss1  = iw + SS1_OFF;
  int* ss2  = iw + SS2_OFF;

  // ---- CSR build (4 dispatches) ----
  hipMemsetAsync(cnt, 0, (size_t)67024 * sizeof(int), stream);
  histrank_k<<<HB, 256, 0, stream>>>(dst0, dst1, dst2, cnt, rank);
  scanpack_k<<<132 + 736, 256, 0, stream>>>(cnt, row0, row1, row2,
                                            Wl0, Wr0, bm0, Wl1, Wr1, bm1);
  fillscatter_k<<<HB, 256, 0, stream>>>(dst0, dst1, dst2, src0, src1, src2,
                                        row0, row1, row2, rank, ss0, ss1, ss2);

  // ---- Layer 0 (split gather + GEMM) ----
  gather_fused_k<<<(N0 * 64 + 255) / 256, 256, 0, stream>>>(x, ss0, row0, am0, N0);
  gemm_mfma_k<224, 28, 64, true, true><<<(N0 + 63) / 64, 256, 0, stream>>>(
      am0, am0, bm0, b0, (void*)h0b, N0, 224, 224);

  // ---- Layer 1 (split gather + GEMM) ----
  gather_mean_b16_k<<<(N1 * 64 + 255) / 256, 256, 0, stream>>>(
      h0bu, ss1, row1, mean1u, N1);
  gemm_mfma_k<512, 32, 32, true, false><<<(N1 + 31) / 32, 256, 0, stream>>>(
      mean1, h0b, bm1, b1, (void*)h1, N1, 256, 256);

  // ---- Layer 2 (fused final) ----
  final_fused_k<<<N2 / 4, 64, 0, stream>>>(h1, ss2, row2, Wl2, Wr2, b2, out);
}

// Round 12
// 255.950 us; speedup vs baseline: 1.5185x; 1.0826x over previous
//
#include <hip/hip_runtime.h>
#include <hip/hip_bf16.h>

// GraphSAGE 3-layer. Round 12 = Round 11 + two fixes:
//  (1) gemm0 epilogue: C staged to LDS, written to h0b as coalesced uint4.
//  (2) final kernel: 4 waves/block (wave per row) for 4x latency hiding.

typedef short bf16x8 __attribute__((ext_vector_type(8)));
typedef float f32x4 __attribute__((ext_vector_type(4)));

static __device__ __forceinline__ unsigned short f2bf(float f) {
  unsigned u = __float_as_uint(f);
  unsigned r = u + 0x7FFFu + ((u >> 16) & 1u);  // RNE
  return (unsigned short)(r >> 16);
}
static __device__ __forceinline__ float bf2f_lo(unsigned u) {
  return __uint_as_float(u << 16);
}
static __device__ __forceinline__ float bf2f_hi(unsigned u) {
  return __uint_as_float(u & 0xFFFF0000u);
}
static __device__ __forceinline__ unsigned packbf(float lo, float hi) {
  return ((unsigned)f2bf(hi) << 16) | (unsigned)f2bf(lo);
}

// ---- sizes ----
#define E0C 900000
#define E1C 60000
#define E2C 5120
#define ETC 965120
#define HB  3770       // ceil(ETC/256)

// ---- int-workspace offsets ----
#define ROW0_OFF 0
#define ROW1_OFF 60001
#define ROW2_OFF 66002
#define CNT_OFF  67027
#define RANK_OFF 134051
#define SS0_OFF  1099171
#define SS1_OFF  1999171
#define SS2_OFF  2059171

struct TileGeom { int tin, goff, n, T; };
static __device__ __forceinline__ TileGeom tile_geom(int b) {
  TileGeom g;
  if (b < 118)      { g.tin = b;       g.goff = 0;     g.n = 60000; g.T = 118; }
  else if (b < 130) { g.tin = b - 118; g.goff = 60000; g.n = 6000;  g.T = 12; }
  else              { g.tin = b - 130; g.goff = 66000; g.n = 1024;  g.T = 2; }
  return g;
}

// ---------- hist with rank capture ----------
__global__ __launch_bounds__(256) void histrank_k(
    const int* __restrict__ d0, const int* __restrict__ d1, const int* __restrict__ d2,
    int* __restrict__ cnt, int* __restrict__ rank) {
  int t = blockIdx.x * 256 + threadIdx.x;
  if (t < E0C) {
    rank[t] = atomicAdd(&cnt[d0[t]], 1);
  } else if (t < E0C + E1C) {
    rank[t] = atomicAdd(&cnt[60000 + d1[t - E0C]], 1);
  } else if (t < ETC) {
    rank[t] = atomicAdd(&cnt[66000 + d2[t - E0C - E1C]], 1);
  }
}

// ---------- per-tile scan (prefix direct from cnt) + weight packing ----------
__global__ __launch_bounds__(256) void scanpack_k(
    const int* __restrict__ cnt,
    int* __restrict__ row0, int* __restrict__ row1, int* __restrict__ row2,
    const float* __restrict__ Wl0, const float* __restrict__ Wr0,
    unsigned short* __restrict__ bm0,
    const float* __restrict__ Wl1, const float* __restrict__ Wr1,
    unsigned short* __restrict__ bm1) {
  const int b = blockIdx.x;
  const int tid = threadIdx.x;
  if (b < 132) {
    __shared__ int sc[256];
    const TileGeom g = tile_geom(b);
    int* row = (b < 118) ? row0 : (b < 130 ? row1 : row2);
    int p = 0;
    const int lim = g.tin * 512;
    for (int i = tid; i < lim; i += 256) p += cnt[g.goff + i];
    sc[tid] = p;
    __syncthreads();
    for (int off = 128; off; off >>= 1) {
      if (tid < off) sc[tid] += sc[tid + off];
      __syncthreads();
    }
    const int pref = sc[0];
    __syncthreads();
    const int i0 = g.tin * 512 + 2 * tid;
    const int e0 = (i0 < g.n) ? cnt[g.goff + i0] : 0;
    const int e1 = (i0 + 1 < g.n) ? cnt[g.goff + i0 + 1] : 0;
    sc[tid] = e0 + e1;
    __syncthreads();
    for (int off = 1; off < 256; off <<= 1) {
      int v = (tid >= off) ? sc[tid - off] : 0;
      __syncthreads();
      sc[tid] += v;
      __syncthreads();
    }
    const int excl = sc[tid] - (e0 + e1);
    const int o0 = pref + excl;
    const int o1 = o0 + e0;
    if (i0 < g.n) row[i0] = o0;
    if (i0 + 1 < g.n) row[i0 + 1] = o1;
    if (g.tin == g.T - 1 && tid == 255) row[g.n] = pref + sc[255];
  } else {
    int j = b - 132;
    int n = tid;
    if (j < 224) {
      int k = j;
      float v = 0.f;
      if (k < 100) v = Wl0[(size_t)k * 256 + n];
      else if (k >= 112 && k < 212) v = Wr0[(size_t)(k - 112) * 256 + n];
      bm0[(((size_t)(k >> 3) * 256) + n) * 8 + (k & 7)] = f2bf(v);
    } else {
      int k = j - 224;
      float v = (k < 256) ? Wl1[(size_t)k * 256 + n] : Wr1[(size_t)(k - 256) * 256 + n];
      bm1[(((size_t)(k >> 3) * 256) + n) * 8 + (k & 7)] = f2bf(v);
    }
  }
}

// ---------- atomic-free fill (rank-based) ----------
__global__ __launch_bounds__(256) void fillscatter_k(
    const int* __restrict__ d0, const int* __restrict__ d1, const int* __restrict__ d2,
    const int* __restrict__ s0, const int* __restrict__ s1, const int* __restrict__ s2,
    const int* __restrict__ row0, const int* __restrict__ row1,
    const int* __restrict__ row2, const int* __restrict__ rank,
    int* __restrict__ o0, int* __restrict__ o1, int* __restrict__ o2) {
  int t = blockIdx.x * 256 + threadIdx.x;
  if (t < E0C) {
    o0[row0[d0[t]] + rank[t]] = s0[t];
  } else if (t < E0C + E1C) {
    int e = t - E0C;
    o1[row1[d1[e]] + rank[t]] = s1[e];
  } else if (t < ETC) {
    int e = t - E0C - E1C;
    o2[row2[d2[e]] + rank[t]] = s2[e];
  }
}

// ---------- gather0: wave-per-row mean + self-row conversion, f32 in ----------
__global__ __launch_bounds__(256) void gather_fused_k(
    const float* __restrict__ x, const int* __restrict__ ss,
    const int* __restrict__ rs, unsigned short* __restrict__ am, int n) {
  int idx = blockIdx.x * 256 + threadIdx.x;
  int w = idx >> 6;
  int f = idx & 63;
  if (w >= n) return;
  const int lo = rs[w];
  const int hi = rs[w + 1];
  float acc0 = 0.f, acc1 = 0.f;
  const int k1 = f + 64;
  int e = lo;
  for (; e + 4 <= hi; e += 4) {
    const float* p0 = x + (size_t)ss[e] * 100;
    const float* p1 = x + (size_t)ss[e + 1] * 100;
    const float* p2 = x + (size_t)ss[e + 2] * 100;
    const float* p3 = x + (size_t)ss[e + 3] * 100;
    acc0 += (p0[f] + p1[f]) + (p2[f] + p3[f]);
    if (k1 < 100) acc1 += (p0[k1] + p1[k1]) + (p2[k1] + p3[k1]);
  }
  for (; e < hi; ++e) {
    const float* p0 = x + (size_t)ss[e] * 100;
    acc0 += p0[f];
    if (k1 < 100) acc1 += p0[k1];
  }
  const float inv = 1.f / (float)max(hi - lo, 1);
  unsigned short* arow = am + (size_t)w * 224;
  arow[f] = f2bf(acc0 * inv);
  if (k1 < 112) arow[k1] = (k1 < 100) ? f2bf(acc1 * inv) : (unsigned short)0;
  const float* xrow = x + (size_t)w * 100;
  arow[112 + f] = f2bf(xrow[f]);
  if (k1 < 112) arow[112 + k1] = (k1 < 100) ? f2bf(xrow[k1]) : (unsigned short)0;
}

// ---------- gather1: wave-per-row mean over bf16 h0 rows ----------
__global__ __launch_bounds__(256) void gather_mean_b16_k(
    const unsigned* __restrict__ xbu, const int* __restrict__ ss,
    const int* __restrict__ rs, unsigned* __restrict__ meanu, int n) {
  int idx = blockIdx.x * 256 + threadIdx.x;
  int w = idx >> 6;
  int f = idx & 63;
  if (w >= n) return;
  const int lo = rs[w];
  const int hi = rs[w + 1];
  float a0l = 0.f, a0h = 0.f, a1l = 0.f, a1h = 0.f;
  int e = lo;
  for (; e + 2 <= hi; e += 2) {
    const unsigned* p0 = xbu + (size_t)ss[e] * 128;
    const unsigned* p1 = xbu + (size_t)ss[e + 1] * 128;
    unsigned u0a = p0[f], u0b = p0[f + 64];
    unsigned u1a = p1[f], u1b = p1[f + 64];
    a0l += bf2f_lo(u0a) + bf2f_lo(u1a);
    a0h += bf2f_hi(u0a) + bf2f_hi(u1a);
    a1l += bf2f_lo(u0b) + bf2f_lo(u1b);
    a1h += bf2f_hi(u0b) + bf2f_hi(u1b);
  }
  for (; e < hi; ++e) {
    const unsigned* p0 = xbu + (size_t)ss[e] * 128;
    unsigned ua = p0[f], ub = p0[f + 64];
    a0l += bf2f_lo(ua); a0h += bf2f_hi(ua);
    a1l += bf2f_lo(ub); a1h += bf2f_hi(ub);
  }
  const float inv = 1.f / (float)max(hi - lo, 1);
  meanu[(size_t)w * 128 + f] = packbf(a0l * inv, a0h * inv);
  meanu[(size_t)w * 128 + f + 64] = packbf(a1l * inv, a1h * inv);
}

// ---------- gemm0: MFMA GEMM K=224, MBLK=64, bf16 out via LDS-coalesced epilogue ----------
__global__ __launch_bounds__(256) void gemm0_k(
    const unsigned short* __restrict__ A, const unsigned short* __restrict__ Bp,
    const float* __restrict__ bias, unsigned short* __restrict__ h0b, int M) {
  constexpr int LDA = 232;          // 224 + 8 shorts
  constexpr int LDC = 264;          // 256 + 8 shorts
  __shared__ unsigned short Sh[64 * LDC];   // 33792 B; reused for A (needs 64*232)

  const int row0 = blockIdx.x * 64;
  // stage A tile
  for (int t = threadIdx.x; t < 64 * 28; t += 256) {
    int r = t / 28;
    int c = t - r * 28;
    *reinterpret_cast<uint4*>(&Sh[r * LDA + c * 8]) =
        *reinterpret_cast<const uint4*>(A + (size_t)(row0 + r) * 224 + c * 8);
  }
  __syncthreads();

  const int wid = threadIdx.x >> 6;
  const int l = threadIdx.x & 63;
  const int l15 = l & 15;
  const int lhi = l >> 4;

  f32x4 acc[4][4];
#pragma unroll
  for (int rt = 0; rt < 4; ++rt)
#pragma unroll
    for (int ct = 0; ct < 4; ++ct) acc[rt][ct] = (f32x4){0.f, 0.f, 0.f, 0.f};

  for (int kc = 0; kc < 7; ++kc) {
    bf16x8 a[4], b[4];
#pragma unroll
    for (int rt = 0; rt < 4; ++rt)
      a[rt] = *reinterpret_cast<const bf16x8*>(
          &Sh[(rt * 16 + l15) * LDA + kc * 32 + lhi * 8]);
#pragma unroll
    for (int ct = 0; ct < 4; ++ct) {
      int n = wid * 64 + ct * 16 + l15;
      b[ct] = *reinterpret_cast<const bf16x8*>(
          Bp + ((size_t)(kc * 4 + lhi) * 256 + n) * 8);
    }
#pragma unroll
    for (int rt = 0; rt < 4; ++rt)
#pragma unroll
      for (int ct = 0; ct < 4; ++ct)
        acc[rt][ct] = __builtin_amdgcn_mfma_f32_16x16x32_bf16(a[rt], b[ct],
                                                              acc[rt][ct], 0, 0, 0);
  }
  __syncthreads();   // done reading A from Sh

  // stage C into LDS (bf16), then coalesced uint4 writes
#pragma unroll
  for (int rt = 0; rt < 4; ++rt) {
#pragma unroll
    for (int ct = 0; ct < 4; ++ct) {
      int col = wid * 64 + ct * 16 + l15;
      float bv = bias[col];
#pragma unroll
      for (int r = 0; r < 4; ++r) {
        int rr = rt * 16 + lhi * 4 + r;
        Sh[rr * LDC + col] = f2bf(fmaxf(acc[rt][ct][r] + bv, 0.f));
      }
    }
  }
  __syncthreads();

  const int mrem = M - row0;
  for (int t = threadIdx.x; t < 64 * 32; t += 256) {
    int r = t >> 5;
    int c = t & 31;
    if (r < mrem) {
      *reinterpret_cast<uint4*>(h0b + (size_t)(row0 + r) * 256 + c * 8) =
          *reinterpret_cast<const uint4*>(&Sh[r * LDC + c * 8]);
    }
  }
}

// ---------- gemm1: MFMA GEMM K=512 (two-pointer A), f32 out ----------
__global__ __launch_bounds__(256) void gemm1_k(
    const unsigned short* __restrict__ A1, const unsigned short* __restrict__ A2,
    const unsigned short* __restrict__ Bp, const float* __restrict__ bias,
    float* __restrict__ h1, int M) {
  constexpr int LDA = 520;
  __shared__ unsigned short As[32 * LDA];

  const int row0 = blockIdx.x * 32;
  for (int t = threadIdx.x; t < 32 * 64; t += 256) {
    int r = t >> 6;
    int c = t & 63;
    const unsigned short* src = (c < 32)
        ? (A1 + (size_t)(row0 + r) * 256 + c * 8)
        : (A2 + (size_t)(row0 + r) * 256 + (c - 32) * 8);
    *reinterpret_cast<uint4*>(&As[r * LDA + c * 8]) =
        *reinterpret_cast<const uint4*>(src);
  }
  __syncthreads();

  const int wid = threadIdx.x >> 6;
  const int l = threadIdx.x & 63;
  const int l15 = l & 15;
  const int lhi = l >> 4;

  f32x4 acc[2][4];
#pragma unroll
  for (int rt = 0; rt < 2; ++rt)
#pragma unroll
    for (int ct = 0; ct < 4; ++ct) acc[rt][ct] = (f32x4){0.f, 0.f, 0.f, 0.f};

  for (int kc = 0; kc < 16; ++kc) {
    bf16x8 a[2], b[4];
#pragma unroll
    for (int rt = 0; rt < 2; ++rt)
      a[rt] = *reinterpret_cast<const bf16x8*>(
          &As[(rt * 16 + l15) * LDA + kc * 32 + lhi * 8]);
#pragma unroll
    for (int ct = 0; ct < 4; ++ct) {
      int n = wid * 64 + ct * 16 + l15;
      b[ct] = *reinterpret_cast<const bf16x8*>(
          Bp + ((size_t)(kc * 4 + lhi) * 256 + n) * 8);
    }
#pragma unroll
    for (int rt = 0; rt < 2; ++rt)
#pragma unroll
      for (int ct = 0; ct < 4; ++ct)
        acc[rt][ct] = __builtin_amdgcn_mfma_f32_16x16x32_bf16(a[rt], b[ct],
                                                              acc[rt][ct], 0, 0, 0);
  }

#pragma unroll
  for (int rt = 0; rt < 2; ++rt) {
#pragma unroll
    for (int ct = 0; ct < 4; ++ct) {
      int col = wid * 64 + ct * 16 + l15;
      float bv = bias[col];
#pragma unroll
      for (int r = 0; r < 4; ++r) {
        int row = row0 + rt * 16 + lhi * 4 + r;
        if (row < M)
          h1[(size_t)row * 256 + col] = fmaxf(acc[rt][ct][r] + bv, 0.f);
      }
    }
  }
}

// ---------- final: 4 waves/block, wave per row; gather2+GEMM+log_softmax ----------
__global__ __launch_bounds__(256) void final_fused_k(
    const float* __restrict__ h1, const int* __restrict__ ss,
    const int* __restrict__ rs, const float* __restrict__ Wl,
    const float* __restrict__ Wr, const float* __restrict__ bb,
    float* __restrict__ out) {
  __shared__ float sm[4][256];
  __shared__ float sx[4][256];
  const int w = threadIdx.x >> 6;       // wave id = row within block
  const int f = threadIdx.x & 63;
  const int i = blockIdx.x * 4 + w;

  const int lo = rs[i];
  const int hi = rs[i + 1];
  float a0 = 0.f, a1 = 0.f, a2 = 0.f, a3 = 0.f;
  for (int e = lo; e < hi; ++e) {
    const float* p = h1 + (size_t)ss[e] * 256;
    a0 += p[f]; a1 += p[f + 64]; a2 += p[f + 128]; a3 += p[f + 192];
  }
  const float inv = 1.f / (float)max(hi - lo, 1);
  sm[w][f] = a0 * inv; sm[w][f + 64] = a1 * inv;
  sm[w][f + 128] = a2 * inv; sm[w][f + 192] = a3 * inv;
  const float* q = h1 + (size_t)i * 256;
  sx[w][f] = q[f]; sx[w][f + 64] = q[f + 64];
  sx[w][f + 128] = q[f + 128]; sx[w][f + 192] = q[f + 192];
  // same-wave produced data; no cross-wave sharing -> no barrier needed

  float acc = -1e30f;
  if (f < 47) {
    float b = bb[f];
    float a = b;
    for (int k = 0; k < 256; ++k) {
      a += sm[w][k] * Wl[k * 47 + f] + sx[w][k] * Wr[k * 47 + f];
    }
    acc = a;
  }
  float m = acc;
#pragma unroll
  for (int off = 32; off; off >>= 1) m = fmaxf(m, __shfl_xor(m, off));
  float e2 = (f < 47) ? expf(acc - m) : 0.f;
  float s = e2;
#pragma unroll
  for (int off = 32; off; off >>= 1) s += __shfl_xor(s, off);
  if (f < 47) out[(size_t)i * 47 + f] = acc - m - logf(s);
}

extern "C" void kernel_launch(void* const* d_in, const int* in_sizes, int n_in,
                              void* d_out, int out_size, void* d_ws, size_t ws_size,
                              hipStream_t stream) {
  const float* x    = (const float*)d_in[0];
  const int*   src0 = (const int*)d_in[1];
  const int*   dst0 = (const int*)d_in[2];
  const int*   src1 = (const int*)d_in[3];
  const int*   dst1 = (const int*)d_in[4];
  const int*   src2 = (const int*)d_in[5];
  const int*   dst2 = (const int*)d_in[6];
  const float* Wl0  = (const float*)d_in[7];
  const float* Wr0  = (const float*)d_in[8];
  const float* b0   = (const float*)d_in[9];
  const float* Wl1  = (const float*)d_in[10];
  const float* Wr1  = (const float*)d_in[11];
  const float* b1   = (const float*)d_in[12];
  const float* Wl2  = (const float*)d_in[13];
  const float* Wr2  = (const float*)d_in[14];
  const float* b2   = (const float*)d_in[15];
  float* out = (float*)d_out;

  const int N0 = 60000, N1 = 6000, N2 = 1024;

  // ---- workspace carve-up (bytes, 256-aligned) ----
  char* base = (char*)d_ws;
  unsigned short* bm0  = (unsigned short*)(base);            // 28x256x8 bf16
  unsigned short* bm1  = (unsigned short*)(base + 114688);   // 64x256x8 bf16
  unsigned short* am0  = (unsigned short*)(base + 376832);   // 60032 x 224 bf16
  unsigned short* h0b  = (unsigned short*)(base + 27271168); // 60032 x 256 bf16
  unsigned*       h0bu = (unsigned*)(base + 27271168);
  unsigned short* mean1= (unsigned short*)(base + 58007552); // 6016 x 256 bf16
  unsigned*       mean1u=(unsigned*)(base + 58007552);
  float* h1            = (float*)(base + 61087744);          // 6016 x 256 f32
  int* iw              = (int*)(base + 67248128);
  int* row0 = iw + ROW0_OFF;
  int* row1 = iw + ROW1_OFF;
  int* row2 = iw + ROW2_OFF;
  int* cnt  = iw + CNT_OFF;
  int* rank = iw + RANK_OFF;
  int* ss0  = iw + SS0_OFF;
  int* ss1  = iw + SS1_OFF;
  int* ss2  = iw + SS2_OFF;

  // ---- CSR build ----
  hipMemsetAsync(cnt, 0, (size_t)67024 * sizeof(int), stream);
  histrank_k<<<HB, 256, 0, stream>>>(dst0, dst1, dst2, cnt, rank);
  scanpack_k<<<132 + 736, 256, 0, stream>>>(cnt, row0, row1, row2,
                                            Wl0, Wr0, bm0, Wl1, Wr1, bm1);
  fillscatter_k<<<HB, 256, 0, stream>>>(dst0, dst1, dst2, src0, src1, src2,
                                        row0, row1, row2, rank, ss0, ss1, ss2);

  // ---- Layer 0 ----
  gather_fused_k<<<(N0 * 64 + 255) / 256, 256, 0, stream>>>(x, ss0, row0, am0, N0);
  gemm0_k<<<(N0 + 63) / 64, 256, 0, stream>>>(am0, bm0, b0, h0b, N0);

  // ---- Layer 1 ----
  gather_mean_b16_k<<<(N1 * 64 + 255) / 256, 256, 0, stream>>>(
      h0bu, ss1, row1, mean1u, N1);
  gemm1_k<<<(N1 + 31) / 32, 256, 0, stream>>>(mean1, h0b, bm1, b1, h1, N1);

  // ---- Layer 2 (fused final, wave-per-row) ----
  final_fused_k<<<N2 / 4, 256, 0, stream>>>(h1, ss2, row2, Wl2, Wr2, b2, out);
}